// Round 1
// baseline (196.277 us; speedup 1.0000x reference)
//
#include <hip/hip_runtime.h>
#include <hip/hip_bf16.h>
#include <stdint.h>

#define B_   4
#define N_   10000
#define K_   16
#define D_   256
#define OUT_ 256
#define KDIM 512          // 2*D
#define M_   (B_ * N_)    // 40000

typedef __attribute__((ext_vector_type(8))) short  short8;   // 8 x bf16 (4 VGPRs)
typedef __attribute__((ext_vector_type(4))) float  f32x4;
typedef __attribute__((ext_vector_type(4))) unsigned short ushort4_t;

__device__ inline unsigned short f2bf(float f) {
    __hip_bfloat16 h = __float2bfloat16(f);
    return *reinterpret_cast<unsigned short*>(&h);
}

// ---------------------------------------------------------------------------
// Kernel 1: build h = [x | mean-aggregated neighbors] as bf16, row-major M x 512.
// One block per node n; wave w handles batch b=w; lane handles 4 columns (float4).
// neigh row loaded once per node, shared across the 4 batches.
// ---------------------------------------------------------------------------
__global__ __launch_bounds__(256) void agg_build(const float* __restrict__ x,
                                                 const int*   __restrict__ neigh,
                                                 unsigned short* __restrict__ h) {
    const int n    = blockIdx.x;
    const int tid  = threadIdx.x;
    const int w    = tid >> 6;     // wave id == batch id
    const int lane = tid & 63;

    __shared__ int idx_s[K_];
    if (tid < K_) idx_s[tid] = neigh[n * K_ + tid];
    __syncthreads();

    int cnt = 0;
#pragma unroll
    for (int k = 0; k < K_; ++k) cnt += (idx_s[k] >= 0) ? 1 : 0;
    const float inv = 1.0f / (float)(cnt > 1 ? cnt : 1);

    const int b = w;
    const float4* __restrict__ xr = (const float4*)x;

    float4 self = xr[(size_t)(b * N_ + n) * 64 + lane];
    float4 acc  = make_float4(0.f, 0.f, 0.f, 0.f);
#pragma unroll
    for (int k = 0; k < K_; ++k) {
        int j = idx_s[k];
        if (j >= 0) {
            float4 v = xr[(size_t)(b * N_ + j) * 64 + lane];
            acc.x += v.x; acc.y += v.y; acc.z += v.z; acc.w += v.w;
        }
    }

    const size_t m = (size_t)b * N_ + n;
    ushort4_t s_self, s_agg;
    s_self.x = f2bf(self.x); s_self.y = f2bf(self.y);
    s_self.z = f2bf(self.z); s_self.w = f2bf(self.w);
    s_agg.x  = f2bf(acc.x * inv); s_agg.y = f2bf(acc.y * inv);
    s_agg.z  = f2bf(acc.z * inv); s_agg.w = f2bf(acc.w * inv);

    *(ushort4_t*)(h + m * KDIM +        lane * 4) = s_self;
    *(ushort4_t*)(h + m * KDIM + D_ +   lane * 4) = s_agg;
}

// ---------------------------------------------------------------------------
// Kernel 2: W fp32 (256 x 512 row-major) -> bf16. Already the B^T layout the
// GEMM consumes.
// ---------------------------------------------------------------------------
__global__ __launch_bounds__(256) void wconv(const float* __restrict__ W,
                                             unsigned short* __restrict__ Wb) {
    int g = blockIdx.x * 256 + threadIdx.x;    // 0 .. 32767, 4 elems each
    float4 v = ((const float4*)W)[g];
    ushort4_t s;
    s.x = f2bf(v.x); s.y = f2bf(v.y); s.z = f2bf(v.z); s.w = f2bf(v.w);
    ((ushort4_t*)Wb)[g] = s;
}

// ---------------------------------------------------------------------------
// Kernel 3: out[m,o] = relu( sum_k h[m,k] * Wb[o,k] + bias[o] )
// m97-style: 128x128 tile, 4 waves (each 64x64 = 4x4 MFMA subtiles),
// BK=32, global_load_lds(16B) staging, mfma_f32_16x16x32_bf16.
// A-frag layout: A[m = lane&15][k = (lane>>4)*8 + j]; B-frag identical on B^T.
// C/D layout:    col = lane&15, row = (lane>>4)*4 + reg.
// ---------------------------------------------------------------------------
__global__ __launch_bounds__(256) void gemm_bt(const unsigned short* __restrict__ A,   // M x 512 bf16
                                               const unsigned short* __restrict__ Bm,  // 256 x 512 bf16
                                               const float* __restrict__ bias,
                                               float* __restrict__ out) {
    __shared__ unsigned short As[128 * 32];
    __shared__ unsigned short Bs[128 * 32];

    const int tid    = threadIdx.x;
    const int w      = tid >> 6;
    const int lane   = tid & 63;
    const int tile_m = blockIdx.x * 128;
    const int nt     = blockIdx.y;
    const int wm     = w & 1;
    const int wn     = w >> 1;
    const int q      = lane >> 4;
    const int r16    = lane & 15;

    f32x4 acc[4][4] = {};

    const int lrow = lane >> 2;        // 0..15 (row within a 16-row chunk)
    const int kofs = (lane & 3) * 8;   // 0,8,16,24 (bf16 elems within BK)

    for (int kk = 0; kk < KDIM; kk += 32) {
#pragma unroll
        for (int r = 0; r < 2; ++r) {
            const int row  = w * 32 + r * 16 + lrow;   // 0..127
            int arow = tile_m + row;
            if (arow > M_ - 1) arow = M_ - 1;          // clamp last partial tile
            const unsigned short* ga = A + (size_t)arow * KDIM + kk + kofs;
            __builtin_amdgcn_global_load_lds(
                (const __attribute__((address_space(1))) void*)ga,
                (__attribute__((address_space(3))) void*)(As + (w * 32 + r * 16) * 32),
                16, 0, 0);

            const int brow = nt * 128 + row;           // <= 255, always valid
            const unsigned short* gb = Bm + (size_t)brow * KDIM + kk + kofs;
            __builtin_amdgcn_global_load_lds(
                (const __attribute__((address_space(1))) void*)gb,
                (__attribute__((address_space(3))) void*)(Bs + (w * 32 + r * 16) * 32),
                16, 0, 0);
        }
        __syncthreads();

        short8 a[4], bf[4];
#pragma unroll
        for (int i = 0; i < 4; ++i)
            a[i] = *(const short8*)(As + (wm * 64 + i * 16 + r16) * 32 + q * 8);
#pragma unroll
        for (int j = 0; j < 4; ++j)
            bf[j] = *(const short8*)(Bs + (wn * 64 + j * 16 + r16) * 32 + q * 8);

#pragma unroll
        for (int i = 0; i < 4; ++i)
#pragma unroll
            for (int j = 0; j < 4; ++j)
                acc[i][j] = __builtin_amdgcn_mfma_f32_16x16x32_bf16(a[i], bf[j], acc[i][j], 0, 0, 0);

        __syncthreads();
    }

    // Epilogue: bias + ReLU, fp32 store, mask rows past M_.
    float bj[4];
#pragma unroll
    for (int j = 0; j < 4; ++j)
        bj[j] = bias[nt * 128 + wn * 64 + j * 16 + r16];

#pragma unroll
    for (int i = 0; i < 4; ++i) {
#pragma unroll
        for (int reg = 0; reg < 4; ++reg) {
            const int m = tile_m + wm * 64 + i * 16 + q * 4 + reg;
            if (m < M_) {
                float* orow = out + (size_t)m * OUT_ + nt * 128 + wn * 64;
#pragma unroll
                for (int j = 0; j < 4; ++j) {
                    float v = acc[i][j][reg] + bj[j];
                    orow[j * 16 + r16] = v > 0.f ? v : 0.f;
                }
            }
        }
    }
}

// ---------------------------------------------------------------------------
extern "C" void kernel_launch(void* const* d_in, const int* in_sizes, int n_in,
                              void* d_out, int out_size, void* d_ws, size_t ws_size,
                              hipStream_t stream) {
    const float* x     = (const float*)d_in[0];   // (4, 10000, 256) fp32
    const int*   neigh = (const int*)d_in[1];     // (10000, 16) int32
    const float* W     = (const float*)d_in[2];   // (256, 512) fp32
    const float* bias  = (const float*)d_in[3];   // (256,) fp32
    float*       out   = (float*)d_out;           // (4, 10000, 256) fp32

    unsigned short* Wb = (unsigned short*)d_ws;           // 256*512 bf16 = 262144 B
    unsigned short* h  = Wb + OUT_ * KDIM;                // 40000*512 bf16 = 40.96 MB

    agg_build<<<N_, 256, 0, stream>>>(x, neigh, h);
    wconv<<<128, 256, 0, stream>>>(W, Wb);
    gemm_bt<<<dim3((M_ + 127) / 128, OUT_ / 128), 256, 0, stream>>>(h, Wb, bias, out);
}

// Round 2
// 162.244 us; speedup vs baseline: 1.2098x; 1.2098x over previous
//
#include <hip/hip_runtime.h>
#include <hip/hip_bf16.h>
#include <stdint.h>

#define B_   4
#define N_   10000
#define K_   16
#define D_   256
#define OUT_ 256
#define KDIM 512          // 2*D
#define M_   (B_ * N_)    // 40000

typedef __attribute__((ext_vector_type(8))) short  short8;   // 8 x bf16 (4 VGPRs)
typedef __attribute__((ext_vector_type(4))) float  f32x4;
typedef __attribute__((ext_vector_type(4))) unsigned short ushort4_t;

__device__ inline unsigned short f2bf(float f) {
    __hip_bfloat16 h = __float2bfloat16(f);
    return *reinterpret_cast<unsigned short*>(&h);
}
__device__ inline float bf2f(unsigned short u) {
    unsigned int v = ((unsigned int)u) << 16;
    return __builtin_bit_cast(float, v);
}

// ---------------------------------------------------------------------------
// Kernel 1: x fp32 (B,N,D) -> (a) self half of h (bf16, row m=b*N+n, cols 0:256)
//                            (b) xg bf16 in gather-friendly (N,B,D) layout
// One block per node; wave = batch; lane handles 4 columns.
// ---------------------------------------------------------------------------
__global__ __launch_bounds__(256) void xprep(const float* __restrict__ x,
                                             unsigned short* __restrict__ h,
                                             unsigned short* __restrict__ xg) {
    const int n    = blockIdx.x;
    const int b    = threadIdx.x >> 6;
    const int lane = threadIdx.x & 63;

    float4 v = ((const float4*)x)[(size_t)(b * N_ + n) * 64 + lane];
    ushort4_t s;
    s.x = f2bf(v.x); s.y = f2bf(v.y); s.z = f2bf(v.z); s.w = f2bf(v.w);

    *(ushort4_t*)(h  + ((size_t)b * N_ + n) * KDIM + lane * 4) = s;
    *(ushort4_t*)(xg + ((size_t)n * B_ + b) * D_   + lane * 4) = s;
}

// ---------------------------------------------------------------------------
// Kernel 2: mean-aggregate neighbors from xg (N,B,D bf16; node row = 2 KB
// contiguous for all 4 batches) -> agg half of h. Wave = batch.
// ---------------------------------------------------------------------------
__global__ __launch_bounds__(256) void agg_build2(const unsigned short* __restrict__ xg,
                                                  const int*            __restrict__ neigh,
                                                  unsigned short*       __restrict__ h) {
    const int n    = blockIdx.x;
    const int tid  = threadIdx.x;
    const int b    = tid >> 6;
    const int lane = tid & 63;

    __shared__ int idx_s[K_];
    if (tid < K_) idx_s[tid] = neigh[n * K_ + tid];
    __syncthreads();

    int cnt = 0;
#pragma unroll
    for (int k = 0; k < K_; ++k) cnt += (idx_s[k] >= 0) ? 1 : 0;
    const float inv = 1.0f / (float)(cnt > 1 ? cnt : 1);

    float ax = 0.f, ay = 0.f, az = 0.f, aw = 0.f;
#pragma unroll
    for (int k = 0; k < K_; ++k) {
        int j = idx_s[k];
        if (j >= 0) {
            ushort4_t v = *(const ushort4_t*)(xg + ((size_t)j * B_ + b) * D_ + lane * 4);
            ax += bf2f(v.x); ay += bf2f(v.y); az += bf2f(v.z); aw += bf2f(v.w);
        }
    }

    ushort4_t s;
    s.x = f2bf(ax * inv); s.y = f2bf(ay * inv);
    s.z = f2bf(az * inv); s.w = f2bf(aw * inv);
    *(ushort4_t*)(h + ((size_t)b * N_ + n) * KDIM + D_ + lane * 4) = s;
}

// ---------------------------------------------------------------------------
// Kernel 3: W fp32 (256 x 512 row-major) -> bf16 (the B^T layout the GEMM wants)
// ---------------------------------------------------------------------------
__global__ __launch_bounds__(256) void wconv(const float* __restrict__ W,
                                             unsigned short* __restrict__ Wb) {
    int g = blockIdx.x * 256 + threadIdx.x;    // 0 .. 32767, 4 elems each
    float4 v = ((const float4*)W)[g];
    ushort4_t s;
    s.x = f2bf(v.x); s.y = f2bf(v.y); s.z = f2bf(v.z); s.w = f2bf(v.w);
    ((ushort4_t*)Wb)[g] = s;
}

// ---------------------------------------------------------------------------
// Kernel 4: out[m,o] = relu( sum_k h[m,k] * Wb[o,k] + bias[o] )
// 64 x 256 tile per block (625 blocks, exact fit -> no masking). 4 waves,
// wave w computes rows 0..63 x cols [w*64, w*64+64). BK=32, 16 K-iters.
// Staging: 20 x 1KB global_load_lds chunks (As 4 KB + Bs 16 KB), 5 per wave.
// A read ONCE per block (vs twice in the 128x128 2-col-tile version).
// A-frag: A[m=lane&15][k=(lane>>4)*8+j]; C/D: col=lane&15, row=(lane>>4)*4+reg.
// ---------------------------------------------------------------------------
__global__ __launch_bounds__(256) void gemm_bt2(const unsigned short* __restrict__ A,   // M x 512 bf16
                                                const unsigned short* __restrict__ Bm,  // 256 x 512 bf16
                                                const float* __restrict__ bias,
                                                float* __restrict__ out) {
    __shared__ unsigned short As[64 * 32];    //  4 KB
    __shared__ unsigned short Bs[256 * 32];   // 16 KB

    const int tid    = threadIdx.x;
    const int w      = tid >> 6;
    const int lane   = tid & 63;
    const int tile_m = blockIdx.x * 64;
    const int q      = lane >> 4;
    const int r16    = lane & 15;

    f32x4 acc[4][4] = {};

    const int crow = lane >> 2;        // 0..15: row within a 16-row chunk
    const int kofs = (lane & 3) * 8;   // bf16 elems within BK

    for (int kk = 0; kk < KDIM; kk += 32) {
#pragma unroll
        for (int t = 0; t < 5; ++t) {
            const int c = w * 5 + t;               // chunk 0..19
            if (c < 4) {                           // A chunks: rows c*16..c*16+15
                const int row = c * 16 + crow;
                const unsigned short* ga = A + (size_t)(tile_m + row) * KDIM + kk + kofs;
                __builtin_amdgcn_global_load_lds(
                    (const __attribute__((address_space(1))) void*)ga,
                    (__attribute__((address_space(3))) void*)(As + c * 512),
                    16, 0, 0);
            } else {                               // B chunks: rows (c-4)*16..
                const int row = (c - 4) * 16 + crow;
                const unsigned short* gb = Bm + (size_t)row * KDIM + kk + kofs;
                __builtin_amdgcn_global_load_lds(
                    (const __attribute__((address_space(1))) void*)gb,
                    (__attribute__((address_space(3))) void*)(Bs + (c - 4) * 512),
                    16, 0, 0);
            }
        }
        __syncthreads();

        short8 a[4], bf[4];
#pragma unroll
        for (int i = 0; i < 4; ++i)
            a[i] = *(const short8*)(As + (i * 16 + r16) * 32 + q * 8);
#pragma unroll
        for (int j = 0; j < 4; ++j)
            bf[j] = *(const short8*)(Bs + (w * 64 + j * 16 + r16) * 32 + q * 8);

#pragma unroll
        for (int i = 0; i < 4; ++i)
#pragma unroll
            for (int j = 0; j < 4; ++j)
                acc[i][j] = __builtin_amdgcn_mfma_f32_16x16x32_bf16(a[i], bf[j], acc[i][j], 0, 0, 0);

        __syncthreads();
    }

    // Epilogue: bias + ReLU. 40000 = 625*64 -> no row masking needed.
    float bj[4];
#pragma unroll
    for (int j = 0; j < 4; ++j)
        bj[j] = bias[w * 64 + j * 16 + r16];

#pragma unroll
    for (int i = 0; i < 4; ++i) {
#pragma unroll
        for (int reg = 0; reg < 4; ++reg) {
            const int m = tile_m + i * 16 + q * 4 + reg;
            float* orow = out + (size_t)m * OUT_ + w * 64;
#pragma unroll
            for (int j = 0; j < 4; ++j) {
                float v = acc[i][j][reg] + bj[j];
                orow[j * 16 + r16] = v > 0.f ? v : 0.f;
            }
        }
    }
}

// ---------------------------------------------------------------------------
extern "C" void kernel_launch(void* const* d_in, const int* in_sizes, int n_in,
                              void* d_out, int out_size, void* d_ws, size_t ws_size,
                              hipStream_t stream) {
    const float* x     = (const float*)d_in[0];   // (4, 10000, 256) fp32
    const int*   neigh = (const int*)d_in[1];     // (10000, 16) int32/int64->int32 low words? (harness gives int)
    const float* W     = (const float*)d_in[2];   // (256, 512) fp32
    const float* bias  = (const float*)d_in[3];   // (256,) fp32
    float*       out   = (float*)d_out;           // (4, 10000, 256) fp32

    unsigned short* Wb = (unsigned short*)d_ws;               // 256*512  bf16 = 0.26 MB
    unsigned short* h  = Wb + OUT_ * KDIM;                    // 40000*512 bf16 = 40.96 MB
    unsigned short* xg = h + (size_t)M_ * KDIM;               // 10000*4*256 bf16 = 20.48 MB

    xprep<<<N_, 256, 0, stream>>>(x, h, xg);
    wconv<<<128, 256, 0, stream>>>(W, Wb);
    agg_build2<<<N_, 256, 0, stream>>>(xg, neigh, h);
    gemm_bt2<<<M_ / 64, 256, 0, stream>>>(h, Wb, bias, out);
}

// Round 3
// 158.564 us; speedup vs baseline: 1.2378x; 1.0232x over previous
//
#include <hip/hip_runtime.h>
#include <hip/hip_bf16.h>
#include <stdint.h>

#define B_   4
#define N_   10000
#define K_   16
#define D_   256
#define OUT_ 256
#define KDIM 512          // 2*D
#define M_   (B_ * N_)    // 40000

// A-tile chunk layout: 16 chunks (BK=32 each) of [64 rows][32 cols],
// chunk stride padded +8 ushorts (16 B) to spread phase-1 write banks.
#define CH_STRIDE 2056    // ushorts per chunk (2048 + 8)

typedef __attribute__((ext_vector_type(8))) short          short8;    // 8 x bf16 for MFMA
typedef __attribute__((ext_vector_type(8))) unsigned short ushort8;
typedef __attribute__((ext_vector_type(4))) float          f32x4;
typedef __attribute__((ext_vector_type(4))) unsigned short ushort4_t;

__device__ inline unsigned short f2bf(float f) {
    __hip_bfloat16 h = __float2bfloat16(f);
    return *reinterpret_cast<unsigned short*>(&h);
}
__device__ inline float bf2f(unsigned short u) {
    unsigned int v = ((unsigned int)u) << 16;
    return __builtin_bit_cast(float, v);
}

// ---------------------------------------------------------------------------
// Kernel 1: x fp32 (B,N,D) -> xg bf16 in gather-friendly (N,B,D) layout.
// 2 nodes per block; thread t handles (n, b, 8 cols): 2 float4 reads, 1
// ushort8 (16 B) write. Fully coalesced both sides.
// ---------------------------------------------------------------------------
__global__ __launch_bounds__(256) void xprep2(const float* __restrict__ x,
                                              unsigned short* __restrict__ xg) {
    const int t  = threadIdx.x;
    const int n  = blockIdx.x * 2 + (t >> 7);      // node
    const int b  = (t >> 5) & 3;                   // batch
    const int c0 = (t & 31) * 8;                   // col base

    const float4* xr = (const float4*)(x + ((size_t)b * N_ + n) * D_ + c0);
    float4 v0 = xr[0];
    float4 v1 = xr[1];
    ushort8 s;
    s[0] = f2bf(v0.x); s[1] = f2bf(v0.y); s[2] = f2bf(v0.z); s[3] = f2bf(v0.w);
    s[4] = f2bf(v1.x); s[5] = f2bf(v1.y); s[6] = f2bf(v1.z); s[7] = f2bf(v1.w);
    *(ushort8*)(xg + ((size_t)n * B_ + b) * D_ + c0) = s;
}

// ---------------------------------------------------------------------------
// Kernel 2: W fp32 (256 x 512 row-major) -> bf16 (B^T layout for the GEMM)
// ---------------------------------------------------------------------------
__global__ __launch_bounds__(256) void wconv(const float* __restrict__ W,
                                             unsigned short* __restrict__ Wb) {
    int g = blockIdx.x * 256 + threadIdx.x;
    float4 v = ((const float4*)W)[g];
    ushort4_t s;
    s.x = f2bf(v.x); s.y = f2bf(v.y); s.z = f2bf(v.z); s.w = f2bf(v.w);
    ((ushort4_t*)Wb)[g] = s;
}

// ---------------------------------------------------------------------------
// Kernel 3 (fused): block = 16 nodes x 4 batches = 64 output rows.
// Phase 1: gather+mean neighbors from xg -> A-tile (64x512 bf16) resident in
//          LDS, chunked [16][64][32] (+pad). A-row ar = node*4 + batch.
// Phase 2: K-loop, A from LDS, B-fragments straight from global (L2-resident
//          256 KB), 16 MFMA per iter, NO barriers in the loop.
// Epilogue: bias + ReLU, fp32 stores to out[m = b*N + n].
// ---------------------------------------------------------------------------
__global__ __launch_bounds__(256) void fused_gemm(const unsigned short* __restrict__ xg,
                                                  const int*            __restrict__ neigh,
                                                  const unsigned short* __restrict__ Bm,
                                                  const float*          __restrict__ bias,
                                                  float*                __restrict__ out) {
    __shared__ unsigned short As[16 * CH_STRIDE];   // 65792 B
    __shared__ int idx_s[256];                      // 16 nodes x 16 neighbors

    const int tid = threadIdx.x;
    const int n0  = blockIdx.x * 16;

    idx_s[tid] = neigh[n0 * K_ + tid];
    __syncthreads();

    // ---- Phase 1: 8 groups of 32 lanes; each group does 8 row-tasks. ----
    const int grp = tid >> 5;
    const int gl  = tid & 31;
    const int ch  = gl >> 2;            // 0..7: chunk within a 256-col half
    const int off = (gl & 3) * 8;       // ushort offset within 32-col chunk

    for (int t = 0; t < 8; ++t) {
        const int ar   = grp * 8 + t;   // A-row 0..63
        const int node = ar >> 2;
        const int b    = ar & 3;

        float acc[8] = {0.f, 0.f, 0.f, 0.f, 0.f, 0.f, 0.f, 0.f};
        int cnt = 0;
#pragma unroll
        for (int k = 0; k < K_; ++k) {
            const int j   = idx_s[node * K_ + k];
            const int jc  = j >= 0 ? j : 0;
            const float m = j >= 0 ? 1.f : 0.f;
            cnt += j >= 0 ? 1 : 0;
            ushort8 v = *(const ushort8*)(xg + (((size_t)jc * B_ + b) << 8) + gl * 8);
#pragma unroll
            for (int e = 0; e < 8; ++e) acc[e] += bf2f(v[e]) * m;
        }
        const float inv = 1.0f / (float)(cnt > 1 ? cnt : 1);

        ushort8 s;
#pragma unroll
        for (int e = 0; e < 8; ++e) s[e] = f2bf(acc[e] * inv);
        *(ushort8*)(As + (8 + ch) * CH_STRIDE + ar * 32 + off) = s;           // agg half

        ushort8 sv = *(const ushort8*)(xg + (((size_t)(n0 + node) * B_ + b) << 8) + gl * 8);
        *(ushort8*)(As + ch * CH_STRIDE + ar * 32 + off) = sv;                // self half
    }
    __syncthreads();

    // ---- Phase 2: barrier-free K-loop. ----
    const int w    = tid >> 6;
    const int lane = tid & 63;
    const int q    = lane >> 4;
    const int r16  = lane & 15;

    f32x4 acc2[4][4] = {};

#pragma unroll 4
    for (int c = 0; c < 16; ++c) {        // 16 BK=32 chunks
        short8 a[4], bf[4];
#pragma unroll
        for (int i = 0; i < 4; ++i)
            a[i] = *(const short8*)(As + c * CH_STRIDE + (i * 16 + r16) * 32 + q * 8);
#pragma unroll
        for (int j = 0; j < 4; ++j)
            bf[j] = *(const short8*)(Bm + (size_t)(w * 64 + j * 16 + r16) * KDIM + c * 32 + q * 8);

#pragma unroll
        for (int i = 0; i < 4; ++i)
#pragma unroll
            for (int j = 0; j < 4; ++j)
                acc2[i][j] = __builtin_amdgcn_mfma_f32_16x16x32_bf16(a[i], bf[j], acc2[i][j], 0, 0, 0);
    }

    // ---- Epilogue: bias + ReLU. Row ar -> m = (ar&3)*N + n0 + (ar>>2). ----
    float bj[4];
#pragma unroll
    for (int j = 0; j < 4; ++j)
        bj[j] = bias[w * 64 + j * 16 + r16];

#pragma unroll
    for (int i = 0; i < 4; ++i) {
#pragma unroll
        for (int reg = 0; reg < 4; ++reg) {
            const int ar = i * 16 + q * 4 + reg;
            const size_t m = (size_t)(ar & 3) * N_ + n0 + (ar >> 2);
            float* orow = out + m * OUT_ + w * 64;
#pragma unroll
            for (int j = 0; j < 4; ++j) {
                float v = acc2[i][j][reg] + bj[j];
                orow[j * 16 + r16] = v > 0.f ? v : 0.f;
            }
        }
    }
}

// ---------------------------------------------------------------------------
extern "C" void kernel_launch(void* const* d_in, const int* in_sizes, int n_in,
                              void* d_out, int out_size, void* d_ws, size_t ws_size,
                              hipStream_t stream) {
    const float* x     = (const float*)d_in[0];   // (4, 10000, 256) fp32
    const int*   neigh = (const int*)d_in[1];     // (10000, 16) int32
    const float* W     = (const float*)d_in[2];   // (256, 512) fp32
    const float* bias  = (const float*)d_in[3];   // (256,) fp32
    float*       out   = (float*)d_out;           // (4, 10000, 256) fp32

    unsigned short* Wb = (unsigned short*)d_ws;   // 256*512 bf16 = 0.26 MB
    unsigned short* xg = Wb + OUT_ * KDIM;        // 10000*4*256 bf16 = 20.48 MB

    xprep2<<<N_ / 2, 256, 0, stream>>>(x, xg);
    wconv<<<128, 256, 0, stream>>>(W, Wb);
    fused_gemm<<<N_ / 16, 256, 0, stream>>>(xg, neigh, Wb, bias, out);
}

// Round 4
// 154.699 us; speedup vs baseline: 1.2688x; 1.0250x over previous
//
#include <hip/hip_runtime.h>
#include <hip/hip_bf16.h>
#include <stdint.h>

#define B_   4
#define N_   10000
#define K_   16
#define D_   256
#define OUT_ 256
#define KDIM 512          // 2*D
#define M_   (B_ * N_)    // 40000

// A-tile: 16 chunks (BK=32) of [32 rows][32 cols] bf16.
// Chunk stride padded +8 ushorts (16 B) so phase-1 writes spread banks.
#define CHS 1032          // ushorts per chunk (32*32 + 8); 2064 B, 16B-aligned

typedef __attribute__((ext_vector_type(8))) short          short8;    // MFMA frag
typedef __attribute__((ext_vector_type(8))) unsigned short ushort8;
typedef __attribute__((ext_vector_type(4))) float          f32x4;
typedef __attribute__((ext_vector_type(4))) unsigned short ushort4_t;

__device__ inline unsigned short f2bf(float f) {
    __hip_bfloat16 h = __float2bfloat16(f);
    return *reinterpret_cast<unsigned short*>(&h);
}
__device__ inline float bf2f(unsigned short u) {
    unsigned int v = ((unsigned int)u) << 16;
    return __builtin_bit_cast(float, v);
}

// ---------------------------------------------------------------------------
// Kernel 1 (merged prep): blocks 0..4999  : x fp32 (B,N,D) -> xg bf16 (N,B,D)
//                         blocks 5000..5127: W fp32 -> Wb bf16 (B^T layout)
// ---------------------------------------------------------------------------
__global__ __launch_bounds__(256) void prep(const float* __restrict__ x,
                                            const float* __restrict__ W,
                                            unsigned short* __restrict__ xg,
                                            unsigned short* __restrict__ Wb) {
    const int t = threadIdx.x;
    if (blockIdx.x < 5000) {
        const int n  = blockIdx.x * 2 + (t >> 7);      // node
        const int b  = (t >> 5) & 3;                   // batch
        const int c0 = (t & 31) * 8;                   // col base
        const float4* xr = (const float4*)(x + ((size_t)b * N_ + n) * D_ + c0);
        float4 v0 = xr[0];
        float4 v1 = xr[1];
        ushort8 s;
        s[0] = f2bf(v0.x); s[1] = f2bf(v0.y); s[2] = f2bf(v0.z); s[3] = f2bf(v0.w);
        s[4] = f2bf(v1.x); s[5] = f2bf(v1.y); s[6] = f2bf(v1.z); s[7] = f2bf(v1.w);
        *(ushort8*)(xg + ((size_t)n * B_ + b) * D_ + c0) = s;
    } else {
        int g = (blockIdx.x - 5000) * 256 + t;         // 0..32767, 4 elems each
        float4 v = ((const float4*)W)[g];
        ushort4_t s;
        s.x = f2bf(v.x); s.y = f2bf(v.y); s.z = f2bf(v.z); s.w = f2bf(v.w);
        ((ushort4_t*)Wb)[g] = s;
    }
}

// ---------------------------------------------------------------------------
// Kernel 2 (fused): block = 8 nodes x 4 batches = 32 output rows. Grid 1250.
// LDS 33.5 KB -> 4 blocks/CU (16 waves/CU).
// Phase 1: thread owns (row ar, col-seg of 8): 4 tasks; per task loads all 16
//          neighbor ushort8 into regs (independent -> deep MLP), then sums.
// Phase 2: barrier-free K-loop, A from LDS, B-frags straight from L2-resident
//          Wb. Wave w: rows 0..31 x cols [w*64, w*64+64) = 2x4 MFMA tiles.
// ---------------------------------------------------------------------------
__global__ __launch_bounds__(256, 4) void fused_gemm(const unsigned short* __restrict__ xg,
                                                     const int*            __restrict__ neigh,
                                                     const unsigned short* __restrict__ Bm,
                                                     const float*          __restrict__ bias,
                                                     float*                __restrict__ out) {
    __shared__ unsigned short As[16 * CHS];   // 33024 B
    __shared__ int idx_s[8 * K_];             // 512 B

    const int tid = threadIdx.x;
    const int n0  = blockIdx.x * 8;

    if (tid < 8 * K_) idx_s[tid] = neigh[n0 * K_ + tid];
    __syncthreads();

    // ---- Phase 1: 4 tasks per thread ----
#pragma unroll
    for (int t = 0; t < 4; ++t) {
        const int task = tid + t * 256;          // 0..1023
        const int ar   = task >> 5;              // row 0..31  (= node*4 + b)
        const int seg  = task & 31;              // 8-ushort col segment 0..31
        const int node = ar >> 2;
        const int b    = ar & 3;

        // load idx into regs, compute count
        int jj[K_];
        int cnt = 0;
#pragma unroll
        for (int k = 0; k < K_; ++k) {
            jj[k] = idx_s[node * K_ + k];
            cnt += jj[k] >= 0 ? 1 : 0;
        }

        // 16 independent gather loads (forced batch -> deep MLP)
        ushort8 vv[K_];
#pragma unroll
        for (int k = 0; k < K_; ++k) {
            const int jc = jj[k] >= 0 ? jj[k] : 0;
            vv[k] = *(const ushort8*)(xg + (((size_t)jc * B_ + b) << 8) + seg * 8);
        }
        // self row load (independent too)
        ushort8 sv = *(const ushort8*)(xg + (((size_t)(n0 + node) * B_ + b) << 8) + seg * 8);

        float acc[8] = {0.f, 0.f, 0.f, 0.f, 0.f, 0.f, 0.f, 0.f};
#pragma unroll
        for (int k = 0; k < K_; ++k) {
            const float m = jj[k] >= 0 ? 1.f : 0.f;
#pragma unroll
            for (int e = 0; e < 8; ++e) acc[e] += bf2f(vv[k][e]) * m;
        }
        const float inv = 1.0f / (float)(cnt > 1 ? cnt : 1);

        ushort8 s;
#pragma unroll
        for (int e = 0; e < 8; ++e) s[e] = f2bf(acc[e] * inv);

        const int ch  = seg >> 2;              // chunk within a 256-col half
        const int off = (seg & 3) * 8;
        *(ushort8*)(As + (8 + ch) * CHS + ar * 32 + off) = s;    // agg half
        *(ushort8*)(As + ch       * CHS + ar * 32 + off) = sv;   // self half
    }
    __syncthreads();

    // ---- Phase 2: barrier-free K-loop ----
    const int w    = tid >> 6;
    const int lane = tid & 63;
    const int q    = lane >> 4;
    const int r16  = lane & 15;

    f32x4 acc2[2][4] = {};

#pragma unroll 4
    for (int c = 0; c < 16; ++c) {
        short8 a[2], bf[4];
#pragma unroll
        for (int i = 0; i < 2; ++i)
            a[i] = *(const short8*)(As + c * CHS + (i * 16 + r16) * 32 + q * 8);
#pragma unroll
        for (int j = 0; j < 4; ++j)
            bf[j] = *(const short8*)(Bm + (size_t)(w * 64 + j * 16 + r16) * KDIM + c * 32 + q * 8);

#pragma unroll
        for (int i = 0; i < 2; ++i)
#pragma unroll
            for (int j = 0; j < 4; ++j)
                acc2[i][j] = __builtin_amdgcn_mfma_f32_16x16x32_bf16(a[i], bf[j], acc2[i][j], 0, 0, 0);
    }

    // ---- Epilogue: bias + ReLU. Row ar -> m = (ar&3)*N + n0 + (ar>>2). ----
    float bj[4];
#pragma unroll
    for (int j = 0; j < 4; ++j)
        bj[j] = bias[w * 64 + j * 16 + r16];

#pragma unroll
    for (int i = 0; i < 2; ++i) {
#pragma unroll
        for (int reg = 0; reg < 4; ++reg) {
            const int ar = i * 16 + q * 4 + reg;
            const size_t m = (size_t)(ar & 3) * N_ + n0 + (ar >> 2);
            float* orow = out + m * OUT_ + w * 64;
#pragma unroll
            for (int j = 0; j < 4; ++j) {
                float v = acc2[i][j][reg] + bj[j];
                orow[j * 16 + r16] = v > 0.f ? v : 0.f;
            }
        }
    }
}

// ---------------------------------------------------------------------------
extern "C" void kernel_launch(void* const* d_in, const int* in_sizes, int n_in,
                              void* d_out, int out_size, void* d_ws, size_t ws_size,
                              hipStream_t stream) {
    const float* x     = (const float*)d_in[0];   // (4, 10000, 256) fp32
    const int*   neigh = (const int*)d_in[1];     // (10000, 16) int32
    const float* W     = (const float*)d_in[2];   // (256, 512) fp32
    const float* bias  = (const float*)d_in[3];   // (256,) fp32
    float*       out   = (float*)d_out;           // (4, 10000, 256) fp32

    unsigned short* Wb = (unsigned short*)d_ws;   // 256*512 bf16 = 0.26 MB
    unsigned short* xg = Wb + OUT_ * KDIM;        // 10000*4*256 bf16 = 20.48 MB

    prep<<<5000 + 128, 256, 0, stream>>>(x, W, xg, Wb);
    fused_gemm<<<N_ / 8, 256, 0, stream>>>(xg, neigh, Wb, bias, out);
}

// Round 5
// 140.565 us; speedup vs baseline: 1.3963x; 1.1006x over previous
//
#include <hip/hip_runtime.h>
#include <hip/hip_bf16.h>
#include <stdint.h>

#define B_   4
#define N_   10000
#define K_   16
#define D_   256
#define OUT_ 256
#define KDIM 512          // 2*D
#define M_   (B_ * N_)    // 40000
#define CW   32           // cols per gather chunk (64 B rows)
#define NCH  8            // number of chunks (one per XCD)

typedef __attribute__((ext_vector_type(8))) short          short8;    // MFMA frag
typedef __attribute__((ext_vector_type(8))) unsigned short ushort8;
typedef __attribute__((ext_vector_type(4))) float          f32x4;
typedef __attribute__((ext_vector_type(4))) unsigned short ushort4_t;

__device__ inline unsigned short f2bf(float f) {
    __hip_bfloat16 h = __float2bfloat16(f);
    return *reinterpret_cast<unsigned short*>(&h);
}
__device__ inline float bf2f(unsigned short u) {
    unsigned int v = ((unsigned int)u) << 16;
    return __builtin_bit_cast(float, v);
}

// ---------------------------------------------------------------------------
// Kernel 1 (prep): blocks 0..4999 : x fp32 (B,N,D) ->
//   (a) self half of h: h[b*N+n][0:256] bf16
//   (b) xc bf16 chunk-major (8 chunks)[n][b][32 cols]; chunk = 2.56 MB.
// blocks 5000..5127 : W fp32 -> Wb bf16 (B^T layout for the GEMM).
// ---------------------------------------------------------------------------
__global__ __launch_bounds__(256) void prep(const float* __restrict__ x,
                                            const float* __restrict__ W,
                                            unsigned short* __restrict__ h,
                                            unsigned short* __restrict__ xc,
                                            unsigned short* __restrict__ Wb) {
    const int t = threadIdx.x;
    if (blockIdx.x < 5000) {
        const int n  = blockIdx.x * 2 + (t >> 7);      // node
        const int b  = (t >> 5) & 3;                   // batch
        const int c0 = (t & 31) * 8;                   // col base (multiple of 8)
        const float4* xr = (const float4*)(x + ((size_t)b * N_ + n) * D_ + c0);
        float4 v0 = xr[0];
        float4 v1 = xr[1];
        ushort8 s;
        s[0] = f2bf(v0.x); s[1] = f2bf(v0.y); s[2] = f2bf(v0.z); s[3] = f2bf(v0.w);
        s[4] = f2bf(v1.x); s[5] = f2bf(v1.y); s[6] = f2bf(v1.z); s[7] = f2bf(v1.w);
        // self half of h
        *(ushort8*)(h + ((size_t)b * N_ + n) * KDIM + c0) = s;
        // chunk-major gather table
        const int ch  = c0 >> 5;          // chunk 0..7
        const int col = c0 & 31;          // 0,8,16,24
        *(ushort8*)(xc + (((size_t)ch * N_ + n) * B_ + b) * CW + col) = s;
    } else {
        int g = (blockIdx.x - 5000) * 256 + t;         // 0..32767, 4 elems each
        float4 v = ((const float4*)W)[g];
        ushort4_t s;
        s.x = f2bf(v.x); s.y = f2bf(v.y); s.z = f2bf(v.z); s.w = f2bf(v.w);
        ((ushort4_t*)Wb)[g] = s;
    }
}

// ---------------------------------------------------------------------------
// Kernel 2 (gather_agg): chunk c = blockIdx & 7  -> pins chunk to one XCD
// (consecutive blocks round-robin across XCDs), so each XCD's random gathers
// hit only its own 2.56-MB chunk -> L2-resident.
// Block: 8 nodes x 4 batches = 32 tasks; 8 lanes per task, lane covers 4 cols
// (8-B loads -> vv[16] = 32 VGPRs, low pressure so all 16 loads stay in
// flight). Wave-load = 2 random j rows x 256 B contiguous = 4 line-reqs.
// Writes agg half of h: h[b*N+n][256 + c*32 ..+32].
// ---------------------------------------------------------------------------
__global__ __launch_bounds__(256) void gather_agg(const unsigned short* __restrict__ xc,
                                                  const int*            __restrict__ neigh,
                                                  unsigned short*       __restrict__ h) {
    const int c   = blockIdx.x & 7;
    const int g   = blockIdx.x >> 3;
    const int n0  = g * 8;
    const int tid = threadIdx.x;

    __shared__ int   idx_s[8 * K_];
    __shared__ float inv_s[8];

    if (tid < 8 * K_) idx_s[tid] = neigh[n0 * K_ + tid];
    __syncthreads();
    if (tid < 8) {
        int cnt = 0;
#pragma unroll
        for (int k = 0; k < K_; ++k) cnt += idx_s[tid * K_ + k] >= 0 ? 1 : 0;
        inv_s[tid] = 1.0f / (float)(cnt > 1 ? cnt : 1);
    }
    __syncthreads();

    const int q  = tid & 7;          // 4-col group within chunk
    const int tl = tid >> 3;         // task 0..31
    const int ns = tl >> 2;          // node_sub 0..7
    const int b  = tl & 3;           // batch

    const unsigned short* xcc = xc + (size_t)c * N_ * B_ * CW;

    int jj[K_];
#pragma unroll
    for (int k = 0; k < K_; ++k) jj[k] = idx_s[ns * K_ + k];

    // 16 independent 8-B gather loads
    ushort4_t vv[K_];
#pragma unroll
    for (int k = 0; k < K_; ++k) {
        const int jc = jj[k] >= 0 ? jj[k] : 0;
        vv[k] = *(const ushort4_t*)(xcc + ((size_t)jc * B_ + b) * CW + q * 4);
    }

    float a0 = 0.f, a1 = 0.f, a2 = 0.f, a3 = 0.f;
#pragma unroll
    for (int k = 0; k < K_; ++k) {
        const float m = jj[k] >= 0 ? 1.f : 0.f;
        a0 += bf2f(vv[k].x) * m;
        a1 += bf2f(vv[k].y) * m;
        a2 += bf2f(vv[k].z) * m;
        a3 += bf2f(vv[k].w) * m;
    }
    const float inv = inv_s[ns];

    ushort4_t s;
    s.x = f2bf(a0 * inv); s.y = f2bf(a1 * inv);
    s.z = f2bf(a2 * inv); s.w = f2bf(a3 * inv);
    *(ushort4_t*)(h + ((size_t)b * N_ + n0 + ns) * KDIM + D_ + c * CW + q * 4) = s;
}

// ---------------------------------------------------------------------------
// Kernel 3: out[m,o] = relu( sum_k h[m,k] * Wb[o,k] + bias[o] )
// 64 x 256 tile per block (625 blocks, exact fit). 4 waves; wave w computes
// rows 0..63 x cols [w*64, w*64+64). BK=32, 16 K-iters; global_load_lds(16B).
// (Proven in round 2.)
// ---------------------------------------------------------------------------
__global__ __launch_bounds__(256) void gemm_bt2(const unsigned short* __restrict__ A,   // M x 512 bf16
                                                const unsigned short* __restrict__ Bm,  // 256 x 512 bf16
                                                const float* __restrict__ bias,
                                                float* __restrict__ out) {
    __shared__ unsigned short As[64 * 32];    //  4 KB
    __shared__ unsigned short Bs[256 * 32];   // 16 KB

    const int tid    = threadIdx.x;
    const int w      = tid >> 6;
    const int lane   = tid & 63;
    const int tile_m = blockIdx.x * 64;
    const int q      = lane >> 4;
    const int r16    = lane & 15;

    f32x4 acc[4][4] = {};

    const int crow = lane >> 2;        // 0..15: row within a 16-row chunk
    const int kofs = (lane & 3) * 8;   // bf16 elems within BK

    for (int kk = 0; kk < KDIM; kk += 32) {
#pragma unroll
        for (int t = 0; t < 5; ++t) {
            const int c = w * 5 + t;               // chunk 0..19
            if (c < 4) {                           // A chunks
                const int row = c * 16 + crow;
                const unsigned short* ga = A + (size_t)(tile_m + row) * KDIM + kk + kofs;
                __builtin_amdgcn_global_load_lds(
                    (const __attribute__((address_space(1))) void*)ga,
                    (__attribute__((address_space(3))) void*)(As + c * 512),
                    16, 0, 0);
            } else {                               // B chunks
                const int row = (c - 4) * 16 + crow;
                const unsigned short* gb = Bm + (size_t)row * KDIM + kk + kofs;
                __builtin_amdgcn_global_load_lds(
                    (const __attribute__((address_space(1))) void*)gb,
                    (__attribute__((address_space(3))) void*)(Bs + (c - 4) * 512),
                    16, 0, 0);
            }
        }
        __syncthreads();

        short8 a[4], bf[4];
#pragma unroll
        for (int i = 0; i < 4; ++i)
            a[i] = *(const short8*)(As + (i * 16 + r16) * 32 + q * 8);
#pragma unroll
        for (int j = 0; j < 4; ++j)
            bf[j] = *(const short8*)(Bs + (w * 64 + j * 16 + r16) * 32 + q * 8);

#pragma unroll
        for (int i = 0; i < 4; ++i)
#pragma unroll
            for (int j = 0; j < 4; ++j)
                acc[i][j] = __builtin_amdgcn_mfma_f32_16x16x32_bf16(a[i], bf[j], acc[i][j], 0, 0, 0);

        __syncthreads();
    }

    float bj[4];
#pragma unroll
    for (int j = 0; j < 4; ++j)
        bj[j] = bias[w * 64 + j * 16 + r16];

#pragma unroll
    for (int i = 0; i < 4; ++i) {
#pragma unroll
        for (int reg = 0; reg < 4; ++reg) {
            const int m = tile_m + i * 16 + q * 4 + reg;
            float* orow = out + (size_t)m * OUT_ + w * 64;
#pragma unroll
            for (int j = 0; j < 4; ++j) {
                float v = acc[i][j][reg] + bj[j];
                orow[j * 16 + r16] = v > 0.f ? v : 0.f;
            }
        }
    }
}

// ---------------------------------------------------------------------------
extern "C" void kernel_launch(void* const* d_in, const int* in_sizes, int n_in,
                              void* d_out, int out_size, void* d_ws, size_t ws_size,
                              hipStream_t stream) {
    const float* x     = (const float*)d_in[0];   // (4, 10000, 256) fp32
    const int*   neigh = (const int*)d_in[1];     // (10000, 16) int32
    const float* W     = (const float*)d_in[2];   // (256, 512) fp32
    const float* bias  = (const float*)d_in[3];   // (256,) fp32
    float*       out   = (float*)d_out;           // (4, 10000, 256) fp32

    unsigned short* Wb = (unsigned short*)d_ws;           // 256*512  bf16 = 0.26 MB
    unsigned short* h  = Wb + OUT_ * KDIM;                // 40000*512 bf16 = 40.96 MB
    unsigned short* xc = h + (size_t)M_ * KDIM;           // 8 x 2.56 MB = 20.48 MB

    prep<<<5000 + 128, 256, 0, stream>>>(x, W, h, xc, Wb);
    gather_agg<<<(N_ / 8) * NCH, 256, 0, stream>>>(xc, neigh, h);
    gemm_bt2<<<M_ / 64, 256, 0, stream>>>(h, Wb, bias, out);
}